// Round 1
// baseline (1181.244 us; speedup 1.0000x reference)
//
#include <hip/hip_runtime.h>
#include <math.h>

// RWKV single-token forward, fused into ONE persistent kernel.
// L=12, E=1024, H=4096, V=50277. All data f32.
//
// Design:
//  - 256 blocks x 256 threads (4 waves/block, 1024 waves total). One block per
//    CU -> all blocks co-resident -> a hand-rolled grid barrier is safe.
//  - Per layer, 4 phases separated by grid barriers:
//      P1: k/v/r matvecs (3x [E,E]) + elementwise wkv -> u vector (+aaa,bbb,ccc)
//      P2: outputvv matvec -> sxx
//      P3: key_ffn [H,E] + receptance_ffn [E,E] matvecs -> km, rt (+ddd)
//      P4: value_ffn [E,H] matvec -> x_next
//  - LayerNorms + input mixing are recomputed redundantly per block (tiny,
//    L2-resident) to avoid extra grid barriers.
//  - Grid barrier: agent-scope atomics; release via __threadfence + acq_rel RMW
//    (flushes the XCD L2), acquire fence after spin (invalidates stale L1/L2).
//    Barrier state lives in d_ws[0..255] and is memset to 0 every launch.

constexpr int E = 1024;
constexpr int H = 4096;
constexpr int V = 50277;
constexpr int L = 12;
constexpr int NBLK = 256;
constexpr int NTHR = 256;
constexpr float LN_EPS = 9.999999747378752e-06f;

struct Args {
  const float *statea, *stateb, *statec, *stated, *pre;
  const float *ln1w, *ln1b, *ln2w, *ln2b;
  const float *ak, *ar, *av, *kk, *vv, *rr, *tf, *td, *ovv;
  const float *tmk, *tmr, *kf, *rf, *vf;
  const float *post0, *post1, *post2;
  const int *token;
  float *out;
  float *ws;        // float scratch: u[1024], sxx[1024], x[1024], km[4096]
  unsigned *bar;    // [0]=count, [1]=generation
};

__device__ __forceinline__ void grid_sync(unsigned *cnt, unsigned *gen, unsigned nb) {
  __syncthreads();
  if (threadIdx.x == 0) {
    __threadfence();  // release: flush this block's global writes (agent scope)
    unsigned g0 = __hip_atomic_load(gen, __ATOMIC_RELAXED, __HIP_MEMORY_SCOPE_AGENT);
    unsigned arr = __hip_atomic_fetch_add(cnt, 1u, __ATOMIC_ACQ_REL, __HIP_MEMORY_SCOPE_AGENT);
    if (arr == nb - 1u) {
      __hip_atomic_store(cnt, 0u, __ATOMIC_RELAXED, __HIP_MEMORY_SCOPE_AGENT);
      __hip_atomic_store(gen, g0 + 1u, __ATOMIC_RELEASE, __HIP_MEMORY_SCOPE_AGENT);
    } else {
      while (__hip_atomic_load(gen, __ATOMIC_RELAXED, __HIP_MEMORY_SCOPE_AGENT) == g0) {
        __builtin_amdgcn_s_sleep(2);
      }
      __builtin_amdgcn_fence(__ATOMIC_ACQUIRE, "agent");  // invalidate stale caches
    }
  }
  __syncthreads();
}

__device__ __forceinline__ float wred(float v) {
#pragma unroll
  for (int off = 32; off; off >>= 1) v += __shfl_down(v, off, 64);
  return v;
}

// Load 1024-float vector xg into s_x, return (mean, rstd) for LayerNorm.
__device__ __forceinline__ float2 block_stats(const float *__restrict__ xg,
                                              float *s_x, float *s_red,
                                              int tid, int lane, int wid) {
  __syncthreads();  // protect s_x / s_red reuse
  float4 v = reinterpret_cast<const float4 *>(xg)[tid];
  reinterpret_cast<float4 *>(s_x)[tid] = v;
  float s = v.x + v.y + v.z + v.w;
  float s2 = v.x * v.x + v.y * v.y + v.z * v.z + v.w * v.w;
#pragma unroll
  for (int off = 32; off; off >>= 1) {
    s += __shfl_down(s, off, 64);
    s2 += __shfl_down(s2, off, 64);
  }
  if (lane == 0) { s_red[wid] = s; s_red[4 + wid] = s2; }
  __syncthreads();
  float ts = s_red[0] + s_red[1] + s_red[2] + s_red[3];
  float ts2 = s_red[4] + s_red[5] + s_red[6] + s_red[7];
  float m = ts * (1.0f / E);
  float var = ts2 * (1.0f / E) - m * m;
  return make_float2(m, rsqrtf(var + LN_EPS));
}

__device__ __forceinline__ float dot4(const float4 w, const float4 x) {
  return w.x * x.x + w.y * x.y + w.z * x.z + w.w * x.w;
}

__global__ __launch_bounds__(NTHR) void rwkv_fused(Args a) {
  __shared__ __align__(16) float s_a[4096];  // mixed inputs / u / km / final LN
  __shared__ __align__(16) float s_x[1024];  // raw x or sxx (kept across phases)
  __shared__ __align__(16) float s_y[1024];  // LN output (xy / xx)
  __shared__ float s_red[8];

  const int tid = threadIdx.x;
  const int lane = tid & 63;
  const int wid = tid >> 6;
  const int blk = blockIdx.x;
  const int g = blk * 4 + wid;  // global wave id, 0..1023
  const unsigned nb = gridDim.x;

  float *ws_u = a.ws;
  float *ws_sxx = a.ws + 1024;
  float *ws_x = a.ws + 2048;
  float *ws_km = a.ws + 3072;

  float *out_logits = a.out;
  float *out_aaa = a.out + V;
  float *out_bbb = out_aaa + L * E;
  float *out_ccc = out_bbb + L * E;
  float *out_ddd = out_ccc + L * E;

  const int tok = a.token[0];
  const float *xin = a.pre + (size_t)tok * E;

  const float4 *s4a = reinterpret_cast<const float4 *>(s_a);
  const float4 *s4r = reinterpret_cast<const float4 *>(s_a + 1024);

  float rt_reg = 0.0f;  // per-wave receptance_ffn result (lane 0 valid)

  for (int l = 0; l < L; ++l) {
    const size_t lE = (size_t)l * E;

    // ---------------- Phase 1: LN1 + k/v/r matvecs + wkv elementwise --------
    {
      float2 st = block_stats(xin, s_x, s_red, tid, lane, wid);
#pragma unroll
      for (int j = 0; j < 4; ++j) {
        int e = tid + 256 * j;
        float xy = (s_x[e] - st.x) * st.y * a.ln1w[lE + e] + a.ln1b[lE + e];
        s_y[e] = xy;
        float sa = a.statea[lE + e];
        s_a[e] = xy + a.kk[lE + e] * sa;
        s_a[1024 + e] = xy + a.vv[lE + e] * sa;
        s_a[2048 + e] = xy + a.rr[lE + e] * sa;
      }
      __syncthreads();

      const float4 *kr = reinterpret_cast<const float4 *>(a.ak + (lE + g) * E);
      const float4 *vr = reinterpret_cast<const float4 *>(a.av + (lE + g) * E);
      const float4 *rr = reinterpret_cast<const float4 *>(a.ar + (lE + g) * E);
      float accK = 0.f, accV = 0.f, accR = 0.f;
#pragma unroll
      for (int it = 0; it < 4; ++it) {
        int idx = it * 64 + lane;
        float4 xk = s4a[idx], xv = s4a[256 + idx], xr = s4a[512 + idx];
        accK += dot4(kr[idx], xk);
        accV += dot4(vr[idx], xv);
        accR += dot4(rr[idx], xr);
      }
      accK = wred(accK); accV = wred(accV); accR = wred(accR);
      if (lane == 0) {
        float kx = expf(accK);
        float vv_ = accV;
        float rx = expf(accR) + 1.0f;
        float etf = expf(a.tf[lE + g]);
        float etd = expf(a.td[lE + g]);
        float sb = a.stateb[lE + g], sc = a.statec[lE + g];
        float w_ = sb + etf * kx * vv_;
        float d_ = sc * rx + etf * kx * rx;
        ws_u[g] = w_ / (d_ + 0.001f);
        out_bbb[lE + g] = sb * etd + kx * vv_;
        out_ccc[lE + g] = sc * etd + kx;
      }
      if (tid < 4) out_aaa[lE + blk * 4 + tid] = s_y[blk * 4 + tid];
    }
    grid_sync(a.bar, a.bar + 1, nb);

    // ---------------- Phase 2: outputvv matvec -> sxx -----------------------
    {
#pragma unroll
      for (int j = 0; j < 4; ++j) s_a[tid + 256 * j] = ws_u[tid + 256 * j];
      __syncthreads();
      const float4 *orow = reinterpret_cast<const float4 *>(a.ovv + (lE + g) * E);
      float acc = 0.f;
#pragma unroll
      for (int it = 0; it < 4; ++it) {
        int idx = it * 64 + lane;
        acc += dot4(orow[idx], s4a[idx]);
      }
      acc = wred(acc);
      if (lane == 0) ws_sxx[g] = s_x[g] + acc;  // s_x still holds layer input x
    }
    grid_sync(a.bar, a.bar + 1, nb);

    // ---------------- Phase 3: LN2 + key_ffn (4 rows) + receptance_ffn ------
    {
      float2 st = block_stats(ws_sxx, s_x, s_red, tid, lane, wid);
#pragma unroll
      for (int j = 0; j < 4; ++j) {
        int e = tid + 256 * j;
        float xx = (s_x[e] - st.x) * st.y * a.ln2w[lE + e] + a.ln2b[lE + e];
        s_y[e] = xx;
        float sd = a.stated[lE + e];
        s_a[e] = xx + a.tmk[lE + e] * sd;
        s_a[1024 + e] = xx + a.tmr[lE + e] * sd;
      }
      __syncthreads();

      const float *kfb = a.kf + (size_t)l * H * E;
#pragma unroll
      for (int j = 0; j < 4; j += 2) {
        const float4 *p1 = reinterpret_cast<const float4 *>(kfb + (size_t)(g + j * 1024) * E);
        const float4 *p2 = reinterpret_cast<const float4 *>(kfb + (size_t)(g + (j + 1) * 1024) * E);
        float a1 = 0.f, a2 = 0.f;
#pragma unroll
        for (int it = 0; it < 4; ++it) {
          int idx = it * 64 + lane;
          float4 xv = s4a[idx];
          a1 += dot4(p1[idx], xv);
          a2 += dot4(p2[idx], xv);
        }
        a1 = wred(a1); a2 = wred(a2);
        if (lane == 0) {
          float t1 = fmaxf(a1, 0.f), t2 = fmaxf(a2, 0.f);
          ws_km[g + j * 1024] = t1 * t1;
          ws_km[g + (j + 1) * 1024] = t2 * t2;
        }
      }
      const float4 *rrow = reinterpret_cast<const float4 *>(a.rf + (lE + g) * E);
      float accr = 0.f;
#pragma unroll
      for (int it = 0; it < 4; ++it) {
        int idx = it * 64 + lane;
        accr += dot4(rrow[idx], s4r[idx]);
      }
      accr = wred(accr);
      if (lane == 0) rt_reg = expf(accr) + 1.0f;
      if (tid < 4) out_ddd[lE + blk * 4 + tid] = s_y[blk * 4 + tid];
    }
    grid_sync(a.bar, a.bar + 1, nb);

    // ---------------- Phase 4: value_ffn matvec -> x_next -------------------
    {
#pragma unroll
      for (int j = 0; j < 16; ++j) s_a[tid + 256 * j] = ws_km[tid + 256 * j];
      __syncthreads();
      const float4 *vrow = reinterpret_cast<const float4 *>(a.vf + (lE + g) * H);
      float acc = 0.f;
#pragma unroll
      for (int it = 0; it < 16; ++it) {
        int idx = it * 64 + lane;
        acc += dot4(vrow[idx], s4a[idx]);
      }
      acc = wred(acc);
      // s_x still holds sxx (from phase-3 stats); rt_reg from phase 3.
      if (lane == 0) ws_x[g] = s_x[g] + acc / rt_reg;
    }
    grid_sync(a.bar, a.bar + 1, nb);

    xin = ws_x;
  }

  // ---------------- Final: LN + logits = post2 @ xfin -----------------------
  {
    float2 st = block_stats(ws_x, s_x, s_red, tid, lane, wid);
#pragma unroll
    for (int j = 0; j < 4; ++j) {
      int e = tid + 256 * j;
      s_a[e] = (s_x[e] - st.x) * st.y * a.post0[e] + a.post1[e];
    }
    __syncthreads();

    for (int r = g; r < V; r += 2048) {
      int rB = r + 1024;
      bool hasB = rB < V;
      const float4 *p1 = reinterpret_cast<const float4 *>(a.post2 + (size_t)r * E);
      const float4 *p2 = reinterpret_cast<const float4 *>(a.post2 + (size_t)(hasB ? rB : r) * E);
      float a1 = 0.f, a2 = 0.f;
#pragma unroll
      for (int it = 0; it < 4; ++it) {
        int idx = it * 64 + lane;
        float4 xv = s4a[idx];
        a1 += dot4(p1[idx], xv);
        a2 += dot4(p2[idx], xv);
      }
      a1 = wred(a1); a2 = wred(a2);
      if (lane == 0) {
        out_logits[r] = a1;
        if (hasB) out_logits[rB] = a2;
      }
    }
  }
}

extern "C" void kernel_launch(void *const *d_in, const int *in_sizes, int n_in,
                              void *d_out, int out_size, void *d_ws, size_t ws_size,
                              hipStream_t stream) {
  (void)in_sizes; (void)n_in; (void)out_size; (void)ws_size;
  Args a;
  a.statea = (const float *)d_in[0];
  a.stateb = (const float *)d_in[1];
  a.statec = (const float *)d_in[2];
  a.stated = (const float *)d_in[3];
  a.pre    = (const float *)d_in[4];
  a.ln1w   = (const float *)d_in[5];
  a.ln1b   = (const float *)d_in[6];
  a.ln2w   = (const float *)d_in[7];
  a.ln2b   = (const float *)d_in[8];
  a.ak     = (const float *)d_in[9];
  a.ar     = (const float *)d_in[10];
  a.av     = (const float *)d_in[11];
  a.kk     = (const float *)d_in[12];
  a.vv     = (const float *)d_in[13];
  a.rr     = (const float *)d_in[14];
  a.tf     = (const float *)d_in[15];
  a.td     = (const float *)d_in[16];
  a.ovv    = (const float *)d_in[17];
  a.tmk    = (const float *)d_in[18];
  a.tmr    = (const float *)d_in[19];
  a.kf     = (const float *)d_in[20];
  a.rf     = (const float *)d_in[21];
  a.vf     = (const float *)d_in[22];
  a.post0  = (const float *)d_in[23];
  a.post1  = (const float *)d_in[24];
  a.post2  = (const float *)d_in[25];
  a.token  = (const int *)d_in[26];
  a.out    = (float *)d_out;
  a.bar    = (unsigned *)d_ws;
  a.ws     = (float *)((char *)d_ws + 256);

  // Reset barrier state every call (d_ws is poisoned once before timing).
  hipMemsetAsync(d_ws, 0, 256, stream);
  rwkv_fused<<<NBLK, NTHR, 0, stream>>>(a);
}

// Round 2
// 1151.483 us; speedup vs baseline: 1.0258x; 1.0258x over previous
//
#include <hip/hip_runtime.h>
#include <math.h>

// RWKV single-token forward — ONE persistent kernel, software-pipelined.
// Key change vs round 1: weight rows for phase k+1 are prefetched into
// REGISTERS between barrier-arrive and barrier-wait, so HBM latency and
// grid-barrier resolve overlap instead of serializing. 512-thr blocks
// (8 waves/CU) with a balanced row split so every wave loads in every phase.

constexpr int E = 1024;
constexpr int H = 4096;
constexpr int V = 50277;
constexpr int L = 12;
constexpr int NBLK = 256;
constexpr int NTHR = 512;
constexpr float LN_EPS = 9.999999747378752e-06f;

struct Args {
  const float *statea, *stateb, *statec, *stated, *pre;
  const float *ln1w, *ln1b, *ln2w, *ln2b;
  const float *ak, *ar, *av, *kk, *vv, *rr, *tf, *td, *ovv;
  const float *tmk, *tmr, *kf, *rf, *vf;
  const float *post0, *post1, *post2;
  const int *token;
  float *out;
  float *ws;        // u[1024], sxx[1024], x[1024], km[4096]
  unsigned *bar;    // [0]=count, [1]=generation
};

__device__ __forceinline__ float wred(float v) {
#pragma unroll
  for (int off = 32; off; off >>= 1) v += __shfl_down(v, off, 64);
  return v;
}

__device__ __forceinline__ float dot4(float4 w, float4 x) {
  return w.x * x.x + w.y * x.y + w.z * x.z + w.w * x.w;
}

struct Bar { unsigned g0; bool owner; };

// Arrive: drain this block's work (syncthreads), publish stores (agent release
// fence = L2 writeback), bump the counter. Returns token for the wait half.
__device__ __forceinline__ Bar bar_arrive(unsigned *cnt, unsigned *gen, unsigned nb) {
  __syncthreads();
  Bar t; t.g0 = 0u; t.owner = false;
  if (threadIdx.x == 0) {
    __threadfence();  // release: flush block's global writes agent-wide
    t.g0 = __hip_atomic_load(gen, __ATOMIC_RELAXED, __HIP_MEMORY_SCOPE_AGENT);
    unsigned arr = __hip_atomic_fetch_add(cnt, 1u, __ATOMIC_RELAXED, __HIP_MEMORY_SCOPE_AGENT);
    if (arr == nb - 1u) {
      __hip_atomic_store(cnt, 0u, __ATOMIC_RELAXED, __HIP_MEMORY_SCOPE_AGENT);
      __hip_atomic_store(gen, t.g0 + 1u, __ATOMIC_RELEASE, __HIP_MEMORY_SCOPE_AGENT);
      t.owner = true;
    }
  }
  return t;
}

__device__ __forceinline__ void bar_wait(Bar t, unsigned *gen) {
  if (threadIdx.x == 0) {
    if (!t.owner) {
      while (__hip_atomic_load(gen, __ATOMIC_RELAXED, __HIP_MEMORY_SCOPE_AGENT) == t.g0)
        __builtin_amdgcn_s_sleep(1);
    }
    __builtin_amdgcn_fence(__ATOMIC_ACQUIRE, "agent");  // invalidate stale caches
  }
  __syncthreads();
}

// Load 1024-float vector into s_x (float2/thread), return (mean, rstd).
__device__ __forceinline__ float2 block_stats(const float *__restrict__ xg,
                                              float *s_x, float *s_red,
                                              int tid, int lane, int wid) {
  float2 v = reinterpret_cast<const float2 *>(xg)[tid];
  reinterpret_cast<float2 *>(s_x)[tid] = v;
  float s = v.x + v.y, s2 = v.x * v.x + v.y * v.y;
#pragma unroll
  for (int off = 32; off; off >>= 1) {
    s += __shfl_down(s, off, 64);
    s2 += __shfl_down(s2, off, 64);
  }
  if (lane == 0) { s_red[wid] = s; s_red[8 + wid] = s2; }
  __syncthreads();
  float ts = 0.f, ts2 = 0.f;
#pragma unroll
  for (int i = 0; i < 8; ++i) { ts += s_red[i]; ts2 += s_red[8 + i]; }
  float m = ts * (1.0f / E);
  float var = ts2 * (1.0f / E) - m * m;
  return make_float2(m, rsqrtf(var + LN_EPS));
}

__global__ __launch_bounds__(NTHR) void rwkv_fused(Args a) {
  __shared__ __align__(16) float s_a[4096];   // phase input vectors
  __shared__ __align__(16) float s_x[1024];   // x / sxx (persists across phases)
  __shared__ __align__(16) float s_y[1024];   // LN output (for aaa/ddd)
  __shared__ float s_pp[24];                  // cross-wave partial sums
  __shared__ float s_red[16];
  __shared__ float s_rt[4];

  const int tid = threadIdx.x;
  const int lane = tid & 63;
  const int wid = tid >> 6;        // 0..7
  const int blk = blockIdx.x;
  const int rloc = wid >> 1;       // 0..3  (row within block's group of 4)
  const int h = wid & 1;           // half of the row this wave owns
  const int grow = blk * 4 + rloc; // global E-row 0..1023
  const unsigned nb = gridDim.x;
  unsigned *cnt = a.bar, *gen = a.bar + 1;

  float *ws_u = a.ws, *ws_sxx = a.ws + 1024, *ws_x = a.ws + 2048, *ws_km = a.ws + 3072;
  float *out_logits = a.out;
  float *out_aaa = a.out + V;
  float *out_bbb = out_aaa + L * E;
  float *out_ccc = out_bbb + L * E;
  float *out_ddd = out_ccc + L * E;

  const int tok = a.token[0];
  const float *xin = a.pre + (size_t)tok * E;
  const float4 *s4a = reinterpret_cast<const float4 *>(s_a);

  float4 pw[10];  // prefetched weight fragments (static indices only)

  // ---- initial prefetch: P1 weights for layer 0 (half h of row grow) ----
  {
    const float4 *kr = reinterpret_cast<const float4 *>(a.ak + (size_t)grow * E);
    const float4 *vr = reinterpret_cast<const float4 *>(a.av + (size_t)grow * E);
    const float4 *rr = reinterpret_cast<const float4 *>(a.ar + (size_t)grow * E);
    int b0 = h * 128 + lane;
    pw[0] = kr[b0]; pw[1] = kr[b0 + 64];
    pw[2] = vr[b0]; pw[3] = vr[b0 + 64];
    pw[4] = rr[b0]; pw[5] = rr[b0 + 64];
    asm volatile("" ::: "memory");
  }

  for (int l = 0; l < L; ++l) {
    const size_t lE = (size_t)l * E;

    // ============ P1: LN1 + k/v/r matvecs + wkv elementwise ============
    {
      float2 st = block_stats(xin, s_x, s_red, tid, lane, wid);
#pragma unroll
      for (int j = 0; j < 2; ++j) {
        int e = tid + 512 * j;
        float xy = (s_x[e] - st.x) * st.y * a.ln1w[lE + e] + a.ln1b[lE + e];
        s_y[e] = xy;
        float sa = a.statea[lE + e];
        s_a[e] = xy + a.kk[lE + e] * sa;
        s_a[1024 + e] = xy + a.vv[lE + e] * sa;
        s_a[2048 + e] = xy + a.rr[lE + e] * sa;
      }
      __syncthreads();
      int b0 = h * 128 + lane;
      float accK = dot4(pw[0], s4a[b0]) + dot4(pw[1], s4a[b0 + 64]);
      float accV = dot4(pw[2], s4a[256 + b0]) + dot4(pw[3], s4a[256 + b0 + 64]);
      float accR = dot4(pw[4], s4a[512 + b0]) + dot4(pw[5], s4a[512 + b0 + 64]);
      accK = wred(accK); accV = wred(accV); accR = wred(accR);
      if (lane == 0) {
        s_pp[wid * 3 + 0] = accK;
        s_pp[wid * 3 + 1] = accV;
        s_pp[wid * 3 + 2] = accR;
      }
      __syncthreads();
      if (tid < 4) {
        size_t o = lE + blk * 4 + tid;
        float K = s_pp[(2 * tid) * 3] + s_pp[(2 * tid + 1) * 3];
        float Vv = s_pp[(2 * tid) * 3 + 1] + s_pp[(2 * tid + 1) * 3 + 1];
        float R = s_pp[(2 * tid) * 3 + 2] + s_pp[(2 * tid + 1) * 3 + 2];
        float kx = expf(K), rx = expf(R) + 1.0f;
        float etf = expf(a.tf[o]), etd = expf(a.td[o]);
        float sb = a.stateb[o], sc = a.statec[o];
        float w_ = sb + etf * kx * Vv;
        float d_ = sc * rx + etf * kx * rx;
        ws_u[blk * 4 + tid] = w_ / (d_ + 0.001f);
        out_bbb[o] = sb * etd + kx * Vv;
        out_ccc[o] = sc * etd + kx;
        out_aaa[o] = s_y[blk * 4 + tid];
      }
    }
    {
      Bar t = bar_arrive(cnt, gen, nb);
      // prefetch P2: ovv half-row
      const float4 *orow = reinterpret_cast<const float4 *>(a.ovv + (lE + grow) * E);
      int b0 = h * 128 + lane;
      pw[0] = orow[b0]; pw[1] = orow[b0 + 64];
      asm volatile("" ::: "memory");
      bar_wait(t, gen);
    }

    // ============ P2: sxx = x + ovv @ u ============
    {
      reinterpret_cast<float2 *>(s_a)[tid] = reinterpret_cast<const float2 *>(ws_u)[tid];
      __syncthreads();
      int b0 = h * 128 + lane;
      float acc = dot4(pw[0], s4a[b0]) + dot4(pw[1], s4a[b0 + 64]);
      acc = wred(acc);
      if (lane == 0) s_pp[wid] = acc;
      __syncthreads();
      if (tid < 4) {
        float sxx = s_x[blk * 4 + tid] + s_pp[2 * tid] + s_pp[2 * tid + 1];
        ws_sxx[blk * 4 + tid] = sxx;
      }
    }
    {
      Bar t = bar_arrive(cnt, gen, nb);
      // prefetch P3: two kf rows (full) + rf half-row
      const float *kfb = a.kf + (size_t)l * H * E;
      const float4 *k0 = reinterpret_cast<const float4 *>(kfb + (size_t)(blk * 16 + wid) * E);
      const float4 *k1 = reinterpret_cast<const float4 *>(kfb + (size_t)(blk * 16 + 8 + wid) * E);
      pw[0] = k0[lane];       pw[1] = k0[lane + 64];
      pw[2] = k0[lane + 128]; pw[3] = k0[lane + 192];
      pw[4] = k1[lane];       pw[5] = k1[lane + 64];
      pw[6] = k1[lane + 128]; pw[7] = k1[lane + 192];
      const float4 *rrow = reinterpret_cast<const float4 *>(a.rf + (lE + grow) * E);
      int b0 = h * 128 + lane;
      pw[8] = rrow[b0]; pw[9] = rrow[b0 + 64];
      asm volatile("" ::: "memory");
      bar_wait(t, gen);
    }

    // ============ P3: LN2 + key_ffn (2 rows/wave) + receptance_ffn ============
    {
      float2 st = block_stats(ws_sxx, s_x, s_red, tid, lane, wid);
#pragma unroll
      for (int j = 0; j < 2; ++j) {
        int e = tid + 512 * j;
        float xx = (s_x[e] - st.x) * st.y * a.ln2w[lE + e] + a.ln2b[lE + e];
        s_y[e] = xx;
        float sd = a.stated[lE + e];
        s_a[e] = xx + a.tmk[lE + e] * sd;
        s_a[1024 + e] = xx + a.tmr[lE + e] * sd;
      }
      __syncthreads();
      float k0 = dot4(pw[0], s4a[lane]) + dot4(pw[1], s4a[lane + 64]) +
                 dot4(pw[2], s4a[lane + 128]) + dot4(pw[3], s4a[lane + 192]);
      float k1 = dot4(pw[4], s4a[lane]) + dot4(pw[5], s4a[lane + 64]) +
                 dot4(pw[6], s4a[lane + 128]) + dot4(pw[7], s4a[lane + 192]);
      int b0 = h * 128 + lane;
      float ar_ = dot4(pw[8], s4a[256 + b0]) + dot4(pw[9], s4a[256 + b0 + 64]);
      k0 = wred(k0); k1 = wred(k1); ar_ = wred(ar_);
      if (lane == 0) {
        float t0 = fmaxf(k0, 0.f), t1 = fmaxf(k1, 0.f);
        ws_km[blk * 16 + wid] = t0 * t0;
        ws_km[blk * 16 + 8 + wid] = t1 * t1;
        s_pp[wid] = ar_;
      }
      __syncthreads();
      if (tid < 4) {
        s_rt[tid] = expf(s_pp[2 * tid] + s_pp[2 * tid + 1]) + 1.0f;
        out_ddd[lE + blk * 4 + tid] = s_y[blk * 4 + tid];
      }
    }
    {
      Bar t = bar_arrive(cnt, gen, nb);
      // prefetch P4: vf half-row (2048 floats)
      const float4 *vrow = reinterpret_cast<const float4 *>(a.vf + (lE + grow) * H);
      int b0 = h * 512 + lane;
      pw[0] = vrow[b0];       pw[1] = vrow[b0 + 64];
      pw[2] = vrow[b0 + 128]; pw[3] = vrow[b0 + 192];
      pw[4] = vrow[b0 + 256]; pw[5] = vrow[b0 + 320];
      pw[6] = vrow[b0 + 384]; pw[7] = vrow[b0 + 448];
      asm volatile("" ::: "memory");
      bar_wait(t, gen);
    }

    // ============ P4: x_next = sxx + (vf @ km) / rt ============
    {
      reinterpret_cast<float4 *>(s_a)[tid] = reinterpret_cast<const float4 *>(ws_km)[tid];
      reinterpret_cast<float4 *>(s_a)[tid + 512] = reinterpret_cast<const float4 *>(ws_km)[tid + 512];
      __syncthreads();
      int b0 = h * 512 + lane;
      float acc = dot4(pw[0], s4a[b0]) + dot4(pw[1], s4a[b0 + 64]) +
                  dot4(pw[2], s4a[b0 + 128]) + dot4(pw[3], s4a[b0 + 192]) +
                  dot4(pw[4], s4a[b0 + 256]) + dot4(pw[5], s4a[b0 + 320]) +
                  dot4(pw[6], s4a[b0 + 384]) + dot4(pw[7], s4a[b0 + 448]);
      acc = wred(acc);
      if (lane == 0) s_pp[wid] = acc;
      __syncthreads();
      if (tid < 4) {
        float xn = s_x[blk * 4 + tid] + (s_pp[2 * tid] + s_pp[2 * tid + 1]) / s_rt[tid];
        ws_x[blk * 4 + tid] = xn;
      }
    }
    {
      Bar t = bar_arrive(cnt, gen, nb);
      if (l < L - 1) {
        const size_t lE2 = (size_t)(l + 1) * E;
        const float4 *kr = reinterpret_cast<const float4 *>(a.ak + (lE2 + grow) * E);
        const float4 *vr = reinterpret_cast<const float4 *>(a.av + (lE2 + grow) * E);
        const float4 *rr = reinterpret_cast<const float4 *>(a.ar + (lE2 + grow) * E);
        int b0 = h * 128 + lane;
        pw[0] = kr[b0]; pw[1] = kr[b0 + 64];
        pw[2] = vr[b0]; pw[3] = vr[b0 + 64];
        pw[4] = rr[b0]; pw[5] = rr[b0 + 64];
        asm volatile("" ::: "memory");
      }
      bar_wait(t, gen);
    }

    xin = ws_x;
  }

  // ============ Final: LN + logits = post2 @ xfin ============
  {
    float2 st = block_stats(ws_x, s_x, s_red, tid, lane, wid);
#pragma unroll
    for (int j = 0; j < 2; ++j) {
      int e = tid + 512 * j;
      s_a[e] = (s_x[e] - st.x) * st.y * a.post0[e] + a.post1[e];
    }
    __syncthreads();

    int gw = blk * 8 + wid;  // 0..2047
    for (int r0 = gw; r0 < V; r0 += 4096) {
      int r1 = r0 + 2048;
      bool hasB = r1 < V;
      const float4 *p0 = reinterpret_cast<const float4 *>(a.post2 + (size_t)r0 * E);
      const float4 *p1 = reinterpret_cast<const float4 *>(a.post2 + (size_t)(hasB ? r1 : r0) * E);
      float a0 = dot4(p0[lane], s4a[lane]) + dot4(p0[lane + 64], s4a[lane + 64]) +
                 dot4(p0[lane + 128], s4a[lane + 128]) + dot4(p0[lane + 192], s4a[lane + 192]);
      float a1 = dot4(p1[lane], s4a[lane]) + dot4(p1[lane + 64], s4a[lane + 64]) +
                 dot4(p1[lane + 128], s4a[lane + 128]) + dot4(p1[lane + 192], s4a[lane + 192]);
      a0 = wred(a0); a1 = wred(a1);
      if (lane == 0) {
        out_logits[r0] = a0;
        if (hasB) out_logits[r1] = a1;
      }
    }
  }
}

extern "C" void kernel_launch(void *const *d_in, const int *in_sizes, int n_in,
                              void *d_out, int out_size, void *d_ws, size_t ws_size,
                              hipStream_t stream) {
  (void)in_sizes; (void)n_in; (void)out_size; (void)ws_size;
  Args a;
  a.statea = (const float *)d_in[0];
  a.stateb = (const float *)d_in[1];
  a.statec = (const float *)d_in[2];
  a.stated = (const float *)d_in[3];
  a.pre    = (const float *)d_in[4];
  a.ln1w   = (const float *)d_in[5];
  a.ln1b   = (const float *)d_in[6];
  a.ln2w   = (const float *)d_in[7];
  a.ln2b   = (const float *)d_in[8];
  a.ak     = (const float *)d_in[9];
  a.ar     = (const float *)d_in[10];
  a.av     = (const float *)d_in[11];
  a.kk     = (const float *)d_in[12];
  a.vv     = (const float *)d_in[13];
  a.rr     = (const float *)d_in[14];
  a.tf     = (const float *)d_in[15];
  a.td     = (const float *)d_in[16];
  a.ovv    = (const float *)d_in[17];
  a.tmk    = (const float *)d_in[18];
  a.tmr    = (const float *)d_in[19];
  a.kf     = (const float *)d_in[20];
  a.rf     = (const float *)d_in[21];
  a.vf     = (const float *)d_in[22];
  a.post0  = (const float *)d_in[23];
  a.post1  = (const float *)d_in[24];
  a.post2  = (const float *)d_in[25];
  a.token  = (const int *)d_in[26];
  a.out    = (float *)d_out;
  a.bar    = (unsigned *)d_ws;
  a.ws     = (float *)((char *)d_ws + 256);

  hipMemsetAsync(d_ws, 0, 256, stream);
  rwkv_fused<<<NBLK, NTHR, 0, stream>>>(a);
}

// Round 3
// 275.121 us; speedup vs baseline: 4.2935x; 4.1854x over previous
//
#include <hip/hip_runtime.h>
#include <math.h>

// RWKV single-token forward — ONE persistent kernel.
// Round-3 change: fence-free grid barrier + coherent data path.
//  - Barrier: per-block flag stores (own cacheline, no RMW contention);
//    block 0 polls all flags (1 thread per flag) then publishes `gen`.
//  - NO __threadfence / acquire fences anywhere. All cross-block vectors
//    (u, sxx, km, x) move via agent-scope RELAXED atomics, which bypass the
//    non-coherent per-XCD L2s. __syncthreads() drains vmcnt, so coherent
//    stores are globally visible before the flag store.
//  - Weight rows for the next phase are prefetched into registers between
//    barrier-arrive and barrier-wait (overlaps HBM latency with the barrier).

constexpr int E = 1024;
constexpr int H = 4096;
constexpr int V = 50277;
constexpr int L = 12;
constexpr int NBLK = 256;
constexpr int NTHR = 512;
constexpr float LN_EPS = 9.999999747378752e-06f;

#define SCOPE_AGENT __HIP_MEMORY_SCOPE_AGENT

__device__ __forceinline__ void cstoref(float *p, float v) {
  __hip_atomic_store(p, v, __ATOMIC_RELAXED, SCOPE_AGENT);
}
__device__ __forceinline__ float cloadf(const float *p) {
  return __hip_atomic_load(p, __ATOMIC_RELAXED, SCOPE_AGENT);
}
__device__ __forceinline__ void cstoreu(unsigned *p, unsigned v) {
  __hip_atomic_store(p, v, __ATOMIC_RELAXED, SCOPE_AGENT);
}
__device__ __forceinline__ unsigned cloadu(const unsigned *p) {
  return __hip_atomic_load(p, __ATOMIC_RELAXED, SCOPE_AGENT);
}

struct Args {
  const float *statea, *stateb, *statec, *stated, *pre;
  const float *ln1w, *ln1b, *ln2w, *ln2b;
  const float *ak, *ar, *av, *kk, *vv, *rr, *tf, *td, *ovv;
  const float *tmk, *tmr, *kf, *rf, *vf;
  const float *post0, *post1, *post2;
  const int *token;
  float *out;
  float *ws;        // coherent scratch: u[1024], sxx[1024], x[1024], km[4096]
  unsigned *gen;    // barrier generation word
  unsigned *flags;  // per-block arrival flags, stride 32 dwords (128 B)
};

// Arrive: all block work done + coherent stores drained (syncthreads drains
// vmcnt per wave), then one coherent flag store per block.
__device__ __forceinline__ void bar_arrive(const Args &a, unsigned ep, int blk) {
  __syncthreads();
  if (blk != 0 && threadIdx.x == 0) cstoreu(&a.flags[blk * 32], ep);
}

// Wait: block 0 polls all flags (one thread each) then publishes gen; other
// blocks spin on gen. No fences — data travels via coherent atomics.
__device__ __forceinline__ void bar_wait(const Args &a, unsigned ep, int blk) {
  if (blk == 0) {
    int t = threadIdx.x;
    if (t > 0 && t < NBLK) {
      while (cloadu(&a.flags[t * 32]) < ep) {}
    }
    __syncthreads();
    if (t == 0) cstoreu(a.gen, ep);
  } else {
    if (threadIdx.x == 0) {
      while (cloadu(a.gen) < ep) __builtin_amdgcn_s_sleep(1);
    }
    __syncthreads();
  }
}

__device__ __forceinline__ float wred(float v) {
#pragma unroll
  for (int off = 32; off; off >>= 1) v += __shfl_down(v, off, 64);
  return v;
}

__device__ __forceinline__ float dot4(float4 w, float4 x) {
  return w.x * x.x + w.y * x.y + w.z * x.z + w.w * x.w;
}

// v = this thread's 2 elements of the 1024-vector; stages into s_x and
// returns (mean, rstd).
__device__ __forceinline__ float2 block_stats_v(float2 v, float *s_x, float *s_red,
                                                int tid, int lane, int wid) {
  reinterpret_cast<float2 *>(s_x)[tid] = v;
  float s = v.x + v.y, s2 = v.x * v.x + v.y * v.y;
#pragma unroll
  for (int off = 32; off; off >>= 1) {
    s += __shfl_down(s, off, 64);
    s2 += __shfl_down(s2, off, 64);
  }
  if (lane == 0) { s_red[wid] = s; s_red[8 + wid] = s2; }
  __syncthreads();
  float ts = 0.f, ts2 = 0.f;
#pragma unroll
  for (int i = 0; i < 8; ++i) { ts += s_red[i]; ts2 += s_red[8 + i]; }
  float m = ts * (1.0f / E);
  float var = ts2 * (1.0f / E) - m * m;
  return make_float2(m, rsqrtf(var + LN_EPS));
}

__global__ __launch_bounds__(NTHR) void rwkv_fused(Args a) {
  __shared__ __align__(16) float s_a[4096];
  __shared__ __align__(16) float s_x[1024];
  __shared__ __align__(16) float s_y[1024];
  __shared__ float s_pp[24];
  __shared__ float s_red[16];
  __shared__ float s_rt[4];

  const int tid = threadIdx.x;
  const int lane = tid & 63;
  const int wid = tid >> 6;        // 0..7
  const int blk = blockIdx.x;
  const int rloc = wid >> 1;       // 0..3
  const int h = wid & 1;           // half of the row this wave owns
  const int grow = blk * 4 + rloc; // global E-row 0..1023

  float *ws_u = a.ws, *ws_sxx = a.ws + 1024, *ws_x = a.ws + 2048, *ws_km = a.ws + 3072;
  float *out_logits = a.out;
  float *out_aaa = a.out + V;
  float *out_bbb = out_aaa + L * E;
  float *out_ccc = out_bbb + L * E;
  float *out_ddd = out_ccc + L * E;

  const int tok = a.token[0];
  const float *pre_row = a.pre + (size_t)tok * E;
  const float4 *s4a = reinterpret_cast<const float4 *>(s_a);

  float4 pw[10];
  unsigned ep = 1;

  // initial prefetch: P1 weights for layer 0
  {
    const float4 *kr = reinterpret_cast<const float4 *>(a.ak + (size_t)grow * E);
    const float4 *vr = reinterpret_cast<const float4 *>(a.av + (size_t)grow * E);
    const float4 *rr = reinterpret_cast<const float4 *>(a.ar + (size_t)grow * E);
    int b0 = h * 128 + lane;
    pw[0] = kr[b0]; pw[1] = kr[b0 + 64];
    pw[2] = vr[b0]; pw[3] = vr[b0 + 64];
    pw[4] = rr[b0]; pw[5] = rr[b0 + 64];
    asm volatile("" ::: "memory");
  }

  for (int l = 0; l < L; ++l) {
    const size_t lE = (size_t)l * E;

    // ============ P1: LN1 + k/v/r matvecs + wkv elementwise ============
    {
      float2 v;
      if (l == 0) {
        v = reinterpret_cast<const float2 *>(pre_row)[tid];
      } else {
        v.x = cloadf(ws_x + 2 * tid);
        v.y = cloadf(ws_x + 2 * tid + 1);
      }
      float2 st = block_stats_v(v, s_x, s_red, tid, lane, wid);
#pragma unroll
      for (int j = 0; j < 2; ++j) {
        int e = tid + 512 * j;
        float xy = (s_x[e] - st.x) * st.y * a.ln1w[lE + e] + a.ln1b[lE + e];
        s_y[e] = xy;
        float sa = a.statea[lE + e];
        s_a[e] = xy + a.kk[lE + e] * sa;
        s_a[1024 + e] = xy + a.vv[lE + e] * sa;
        s_a[2048 + e] = xy + a.rr[lE + e] * sa;
      }
      __syncthreads();
      int b0 = h * 128 + lane;
      float accK = dot4(pw[0], s4a[b0]) + dot4(pw[1], s4a[b0 + 64]);
      float accV = dot4(pw[2], s4a[256 + b0]) + dot4(pw[3], s4a[256 + b0 + 64]);
      float accR = dot4(pw[4], s4a[512 + b0]) + dot4(pw[5], s4a[512 + b0 + 64]);
      accK = wred(accK); accV = wred(accV); accR = wred(accR);
      if (lane == 0) {
        s_pp[wid * 3 + 0] = accK;
        s_pp[wid * 3 + 1] = accV;
        s_pp[wid * 3 + 2] = accR;
      }
      __syncthreads();
      if (tid < 4) {
        size_t o = lE + blk * 4 + tid;
        float K = s_pp[(2 * tid) * 3] + s_pp[(2 * tid + 1) * 3];
        float Vv = s_pp[(2 * tid) * 3 + 1] + s_pp[(2 * tid + 1) * 3 + 1];
        float R = s_pp[(2 * tid) * 3 + 2] + s_pp[(2 * tid + 1) * 3 + 2];
        float kx = expf(K), rx = expf(R) + 1.0f;
        float etf = expf(a.tf[o]), etd = expf(a.td[o]);
        float sb = a.stateb[o], sc = a.statec[o];
        float w_ = sb + etf * kx * Vv;
        float d_ = sc * rx + etf * kx * rx;
        cstoref(&ws_u[blk * 4 + tid], w_ / (d_ + 0.001f));
        out_bbb[o] = sb * etd + kx * Vv;
        out_ccc[o] = sc * etd + kx;
        out_aaa[o] = s_y[blk * 4 + tid];
      }
    }
    bar_arrive(a, ep, blk);
    {
      const float4 *orow = reinterpret_cast<const float4 *>(a.ovv + (lE + grow) * E);
      int b0 = h * 128 + lane;
      pw[0] = orow[b0]; pw[1] = orow[b0 + 64];
      asm volatile("" ::: "memory");
    }
    bar_wait(a, ep, blk); ++ep;

    // ============ P2: sxx = x + ovv @ u ============
    {
      s_a[2 * tid] = cloadf(ws_u + 2 * tid);
      s_a[2 * tid + 1] = cloadf(ws_u + 2 * tid + 1);
      __syncthreads();
      int b0 = h * 128 + lane;
      float acc = dot4(pw[0], s4a[b0]) + dot4(pw[1], s4a[b0 + 64]);
      acc = wred(acc);
      if (lane == 0) s_pp[wid] = acc;
      __syncthreads();
      if (tid < 4) {
        float sxx = s_x[blk * 4 + tid] + s_pp[2 * tid] + s_pp[2 * tid + 1];
        cstoref(&ws_sxx[blk * 4 + tid], sxx);
      }
    }
    bar_arrive(a, ep, blk);
    {
      const float *kfb = a.kf + (size_t)l * H * E;
      const float4 *k0 = reinterpret_cast<const float4 *>(kfb + (size_t)(blk * 16 + wid) * E);
      const float4 *k1 = reinterpret_cast<const float4 *>(kfb + (size_t)(blk * 16 + 8 + wid) * E);
      pw[0] = k0[lane];       pw[1] = k0[lane + 64];
      pw[2] = k0[lane + 128]; pw[3] = k0[lane + 192];
      pw[4] = k1[lane];       pw[5] = k1[lane + 64];
      pw[6] = k1[lane + 128]; pw[7] = k1[lane + 192];
      const float4 *rrow = reinterpret_cast<const float4 *>(a.rf + (lE + grow) * E);
      int b0 = h * 128 + lane;
      pw[8] = rrow[b0]; pw[9] = rrow[b0 + 64];
      asm volatile("" ::: "memory");
    }
    bar_wait(a, ep, blk); ++ep;

    // ============ P3: LN2 + key_ffn (2 rows/wave) + receptance_ffn ============
    {
      float2 v;
      v.x = cloadf(ws_sxx + 2 * tid);
      v.y = cloadf(ws_sxx + 2 * tid + 1);
      float2 st = block_stats_v(v, s_x, s_red, tid, lane, wid);
#pragma unroll
      for (int j = 0; j < 2; ++j) {
        int e = tid + 512 * j;
        float xx = (s_x[e] - st.x) * st.y * a.ln2w[lE + e] + a.ln2b[lE + e];
        s_y[e] = xx;
        float sd = a.stated[lE + e];
        s_a[e] = xx + a.tmk[lE + e] * sd;
        s_a[1024 + e] = xx + a.tmr[lE + e] * sd;
      }
      __syncthreads();
      float k0 = dot4(pw[0], s4a[lane]) + dot4(pw[1], s4a[lane + 64]) +
                 dot4(pw[2], s4a[lane + 128]) + dot4(pw[3], s4a[lane + 192]);
      float k1 = dot4(pw[4], s4a[lane]) + dot4(pw[5], s4a[lane + 64]) +
                 dot4(pw[6], s4a[lane + 128]) + dot4(pw[7], s4a[lane + 192]);
      int b0 = h * 128 + lane;
      float ar_ = dot4(pw[8], s4a[256 + b0]) + dot4(pw[9], s4a[256 + b0 + 64]);
      k0 = wred(k0); k1 = wred(k1); ar_ = wred(ar_);
      if (lane == 0) {
        float t0 = fmaxf(k0, 0.f), t1 = fmaxf(k1, 0.f);
        cstoref(&ws_km[blk * 16 + wid], t0 * t0);
        cstoref(&ws_km[blk * 16 + 8 + wid], t1 * t1);
        s_pp[wid] = ar_;
      }
      __syncthreads();
      if (tid < 4) {
        s_rt[tid] = expf(s_pp[2 * tid] + s_pp[2 * tid + 1]) + 1.0f;
        out_ddd[lE + blk * 4 + tid] = s_y[blk * 4 + tid];
      }
    }
    bar_arrive(a, ep, blk);
    {
      const float4 *vrow = reinterpret_cast<const float4 *>(a.vf + (lE + grow) * H);
      int b0 = h * 512 + lane;
      pw[0] = vrow[b0];       pw[1] = vrow[b0 + 64];
      pw[2] = vrow[b0 + 128]; pw[3] = vrow[b0 + 192];
      pw[4] = vrow[b0 + 256]; pw[5] = vrow[b0 + 320];
      pw[6] = vrow[b0 + 384]; pw[7] = vrow[b0 + 448];
      asm volatile("" ::: "memory");
    }
    bar_wait(a, ep, blk); ++ep;

    // ============ P4: x_next = sxx + (vf @ km) / rt ============
    {
#pragma unroll
      for (int j = 0; j < 8; ++j)
        s_a[tid + 512 * j] = cloadf(ws_km + tid + 512 * j);
      __syncthreads();
      int b0 = h * 512 + lane;
      float acc = dot4(pw[0], s4a[b0]) + dot4(pw[1], s4a[b0 + 64]) +
                  dot4(pw[2], s4a[b0 + 128]) + dot4(pw[3], s4a[b0 + 192]) +
                  dot4(pw[4], s4a[b0 + 256]) + dot4(pw[5], s4a[b0 + 320]) +
                  dot4(pw[6], s4a[b0 + 384]) + dot4(pw[7], s4a[b0 + 448]);
      acc = wred(acc);
      if (lane == 0) s_pp[wid] = acc;
      __syncthreads();
      if (tid < 4) {
        float xn = s_x[blk * 4 + tid] + (s_pp[2 * tid] + s_pp[2 * tid + 1]) / s_rt[tid];
        cstoref(&ws_x[blk * 4 + tid], xn);
      }
    }
    bar_arrive(a, ep, blk);
    if (l < L - 1) {
      const size_t lE2 = (size_t)(l + 1) * E;
      const float4 *kr = reinterpret_cast<const float4 *>(a.ak + (lE2 + grow) * E);
      const float4 *vr = reinterpret_cast<const float4 *>(a.av + (lE2 + grow) * E);
      const float4 *rr = reinterpret_cast<const float4 *>(a.ar + (lE2 + grow) * E);
      int b0 = h * 128 + lane;
      pw[0] = kr[b0]; pw[1] = kr[b0 + 64];
      pw[2] = vr[b0]; pw[3] = vr[b0 + 64];
      pw[4] = rr[b0]; pw[5] = rr[b0 + 64];
      asm volatile("" ::: "memory");
    }
    bar_wait(a, ep, blk); ++ep;
  }

  // ============ Final: LN + logits = post2 @ xfin ============
  {
    float2 v;
    v.x = cloadf(ws_x + 2 * tid);
    v.y = cloadf(ws_x + 2 * tid + 1);
    float2 st = block_stats_v(v, s_x, s_red, tid, lane, wid);
#pragma unroll
    for (int j = 0; j < 2; ++j) {
      int e = tid + 512 * j;
      s_a[e] = (s_x[e] - st.x) * st.y * a.post0[e] + a.post1[e];
    }
    __syncthreads();

    int gw = blk * 8 + wid;  // 0..2047
    for (int r0 = gw; r0 < V; r0 += 4096) {
      int r1 = r0 + 2048;
      bool hasB = r1 < V;
      const float4 *p0 = reinterpret_cast<const float4 *>(a.post2 + (size_t)r0 * E);
      const float4 *p1 = reinterpret_cast<const float4 *>(a.post2 + (size_t)(hasB ? r1 : r0) * E);
      float a0 = dot4(p0[lane], s4a[lane]) + dot4(p0[lane + 64], s4a[lane + 64]) +
                 dot4(p0[lane + 128], s4a[lane + 128]) + dot4(p0[lane + 192], s4a[lane + 192]);
      float a1 = dot4(p1[lane], s4a[lane]) + dot4(p1[lane + 64], s4a[lane + 64]) +
                 dot4(p1[lane + 128], s4a[lane + 128]) + dot4(p1[lane + 192], s4a[lane + 192]);
      a0 = wred(a0); a1 = wred(a1);
      if (lane == 0) {
        out_logits[r0] = a0;
        if (hasB) out_logits[r1] = a1;
      }
    }
  }
}

extern "C" void kernel_launch(void *const *d_in, const int *in_sizes, int n_in,
                              void *d_out, int out_size, void *d_ws, size_t ws_size,
                              hipStream_t stream) {
  (void)in_sizes; (void)n_in; (void)out_size; (void)ws_size;
  Args a;
  a.statea = (const float *)d_in[0];
  a.stateb = (const float *)d_in[1];
  a.statec = (const float *)d_in[2];
  a.stated = (const float *)d_in[3];
  a.pre    = (const float *)d_in[4];
  a.ln1w   = (const float *)d_in[5];
  a.ln1b   = (const float *)d_in[6];
  a.ln2w   = (const float *)d_in[7];
  a.ln2b   = (const float *)d_in[8];
  a.ak     = (const float *)d_in[9];
  a.ar     = (const float *)d_in[10];
  a.av     = (const float *)d_in[11];
  a.kk     = (const float *)d_in[12];
  a.vv     = (const float *)d_in[13];
  a.rr     = (const float *)d_in[14];
  a.tf     = (const float *)d_in[15];
  a.td     = (const float *)d_in[16];
  a.ovv    = (const float *)d_in[17];
  a.tmk    = (const float *)d_in[18];
  a.tmr    = (const float *)d_in[19];
  a.kf     = (const float *)d_in[20];
  a.rf     = (const float *)d_in[21];
  a.vf     = (const float *)d_in[22];
  a.post0  = (const float *)d_in[23];
  a.post1  = (const float *)d_in[24];
  a.post2  = (const float *)d_in[25];
  a.token  = (const int *)d_in[26];
  a.out    = (float *)d_out;

  a.gen    = (unsigned *)d_ws;                       // dword 0
  a.flags  = (unsigned *)((char *)d_ws + 128);       // 256 flags, 128 B stride
  a.ws     = (float *)((char *)d_ws + 36864);        // coherent data vectors

  // zero gen + flags each launch (graph-capture safe)
  hipMemsetAsync(d_ws, 0, 36864, stream);
  rwkv_fused<<<NBLK, NTHR, 0, stream>>>(a);
}

// Round 4
// 242.421 us; speedup vs baseline: 4.8727x; 1.1349x over previous
//
#include <hip/hip_runtime.h>
#include <math.h>

// RWKV single-token forward — ONE persistent kernel.
// Round-4 changes:
//  - One-hop all-to-all barrier: each block stores its flag; EVERY block's
//    tid<256 threads poll one flag each (throttled). No master/gen hop.
//  - Cross-block vectors read via coherent 8B/16B loads (global_load_dwordx2/4
//    sc0 sc1 = serve at coherence point), 2-4x fewer LLC requests than 4B atomics.
//  - Logits matvec explicitly double-buffered (loads for iter i+1 in flight
//    during wred of iter i).

constexpr int E = 1024;
constexpr int H = 4096;
constexpr int V = 50277;
constexpr int L = 12;
constexpr int NBLK = 256;
constexpr int NTHR = 512;
constexpr float LN_EPS = 9.999999747378752e-06f;

#define SCOPE_AGENT __HIP_MEMORY_SCOPE_AGENT

__device__ __forceinline__ void cstoref(float *p, float v) {
  __hip_atomic_store(p, v, __ATOMIC_RELAXED, SCOPE_AGENT);
}
__device__ __forceinline__ void cstoreu(unsigned *p, unsigned v) {
  __hip_atomic_store(p, v, __ATOMIC_RELAXED, SCOPE_AGENT);
}
__device__ __forceinline__ unsigned cloadu(const unsigned *p) {
  return __hip_atomic_load(p, __ATOMIC_RELAXED, SCOPE_AGENT);
}

// Coherent (LLC-point) wide loads. Data was written with agent-scope stores,
// so L1/L2 never hold these lines; sc0 sc1 keeps it that way.
__device__ __forceinline__ float2 cload2(const void *p) {
  float2 r;
  asm volatile("global_load_dwordx2 %0, %1, off sc0 sc1\n\t"
               "s_waitcnt vmcnt(0)"
               : "=&v"(r) : "v"(p) : "memory");
  return r;
}
__device__ __forceinline__ void cload4x2(float4 &r0, float4 &r1,
                                         const void *p0, const void *p1) {
  asm volatile("global_load_dwordx4 %0, %2, off sc0 sc1\n\t"
               "global_load_dwordx4 %1, %3, off sc0 sc1\n\t"
               "s_waitcnt vmcnt(0)"
               : "=&v"(r0), "=&v"(r1) : "v"(p0), "v"(p1) : "memory");
}

struct Args {
  const float *statea, *stateb, *statec, *stated, *pre;
  const float *ln1w, *ln1b, *ln2w, *ln2b;
  const float *ak, *ar, *av, *kk, *vv, *rr, *tf, *td, *ovv;
  const float *tmk, *tmr, *kf, *rf, *vf;
  const float *post0, *post1, *post2;
  const int *token;
  float *out;
  float *ws;        // coherent scratch: u[1024], sxx[1024], x[1024], km[4096]
  unsigned *flags;  // per-block arrival flags, stride 32 dwords (128 B)
};

// Arrive: syncthreads drains all waves' stores (compiler emits vmcnt(0) before
// s_barrier), then one coherent flag store.
__device__ __forceinline__ void bar_arrive(const Args &a, unsigned ep, int blk) {
  __syncthreads();
  if (threadIdx.x == 0) cstoreu(&a.flags[blk * 32], ep);
}

// Wait: tid<256 threads each poll one block's flag. One hop: slowest flag
// store -> direct observation. s_sleep throttles poll traffic.
__device__ __forceinline__ void bar_wait(const Args &a, unsigned ep) {
  if (threadIdx.x < NBLK) {
    while (cloadu(&a.flags[threadIdx.x * 32]) < ep)
      __builtin_amdgcn_s_sleep(2);
  }
  __syncthreads();
}

__device__ __forceinline__ float wred(float v) {
#pragma unroll
  for (int off = 32; off; off >>= 1) v += __shfl_down(v, off, 64);
  return v;
}

__device__ __forceinline__ float dot4(float4 w, float4 x) {
  return w.x * x.x + w.y * x.y + w.z * x.z + w.w * x.w;
}

__device__ __forceinline__ float2 block_stats_v(float2 v, float *s_x, float *s_red,
                                                int tid, int lane, int wid) {
  reinterpret_cast<float2 *>(s_x)[tid] = v;
  float s = v.x + v.y, s2 = v.x * v.x + v.y * v.y;
#pragma unroll
  for (int off = 32; off; off >>= 1) {
    s += __shfl_down(s, off, 64);
    s2 += __shfl_down(s2, off, 64);
  }
  if (lane == 0) { s_red[wid] = s; s_red[8 + wid] = s2; }
  __syncthreads();
  float ts = 0.f, ts2 = 0.f;
#pragma unroll
  for (int i = 0; i < 8; ++i) { ts += s_red[i]; ts2 += s_red[8 + i]; }
  float m = ts * (1.0f / E);
  float var = ts2 * (1.0f / E) - m * m;
  return make_float2(m, rsqrtf(var + LN_EPS));
}

__device__ __forceinline__ void loadrow(float4 *d, const float4 *P, int r, int lane) {
  const float4 *p = P + (size_t)r * 256;
  d[0] = p[lane]; d[1] = p[lane + 64]; d[2] = p[lane + 128]; d[3] = p[lane + 192];
}

__global__ __launch_bounds__(NTHR) void rwkv_fused(Args a) {
  __shared__ __align__(16) float s_a[4096];
  __shared__ __align__(16) float s_x[1024];
  __shared__ __align__(16) float s_y[1024];
  __shared__ float s_pp[24];
  __shared__ float s_red[16];
  __shared__ float s_rt[4];

  const int tid = threadIdx.x;
  const int lane = tid & 63;
  const int wid = tid >> 6;        // 0..7
  const int blk = blockIdx.x;
  const int rloc = wid >> 1;       // 0..3
  const int h = wid & 1;           // half of the row this wave owns
  const int grow = blk * 4 + rloc; // global E-row 0..1023

  float *ws_u = a.ws, *ws_sxx = a.ws + 1024, *ws_x = a.ws + 2048, *ws_km = a.ws + 3072;
  float *out_logits = a.out;
  float *out_aaa = a.out + V;
  float *out_bbb = out_aaa + L * E;
  float *out_ccc = out_bbb + L * E;
  float *out_ddd = out_ccc + L * E;

  const int tok = a.token[0];
  const float *pre_row = a.pre + (size_t)tok * E;
  const float4 *s4a = reinterpret_cast<const float4 *>(s_a);

  float4 pw[10];
  unsigned ep = 1;

  // initial prefetch: P1 weights for layer 0
  {
    const float4 *kr = reinterpret_cast<const float4 *>(a.ak + (size_t)grow * E);
    const float4 *vr = reinterpret_cast<const float4 *>(a.av + (size_t)grow * E);
    const float4 *rr = reinterpret_cast<const float4 *>(a.ar + (size_t)grow * E);
    int b0 = h * 128 + lane;
    pw[0] = kr[b0]; pw[1] = kr[b0 + 64];
    pw[2] = vr[b0]; pw[3] = vr[b0 + 64];
    pw[4] = rr[b0]; pw[5] = rr[b0 + 64];
    asm volatile("" ::: "memory");
  }

  for (int l = 0; l < L; ++l) {
    const size_t lE = (size_t)l * E;

    // ============ P1: LN1 + k/v/r matvecs + wkv elementwise ============
    {
      float2 v;
      if (l == 0) {
        v = reinterpret_cast<const float2 *>(pre_row)[tid];
      } else {
        v = cload2(reinterpret_cast<const float2 *>(ws_x) + tid);
      }
      float2 st = block_stats_v(v, s_x, s_red, tid, lane, wid);
#pragma unroll
      for (int j = 0; j < 2; ++j) {
        int e = tid + 512 * j;
        float xy = (s_x[e] - st.x) * st.y * a.ln1w[lE + e] + a.ln1b[lE + e];
        s_y[e] = xy;
        float sa = a.statea[lE + e];
        s_a[e] = xy + a.kk[lE + e] * sa;
        s_a[1024 + e] = xy + a.vv[lE + e] * sa;
        s_a[2048 + e] = xy + a.rr[lE + e] * sa;
      }
      __syncthreads();
      int b0 = h * 128 + lane;
      float accK = dot4(pw[0], s4a[b0]) + dot4(pw[1], s4a[b0 + 64]);
      float accV = dot4(pw[2], s4a[256 + b0]) + dot4(pw[3], s4a[256 + b0 + 64]);
      float accR = dot4(pw[4], s4a[512 + b0]) + dot4(pw[5], s4a[512 + b0 + 64]);
      accK = wred(accK); accV = wred(accV); accR = wred(accR);
      if (lane == 0) {
        s_pp[wid * 3 + 0] = accK;
        s_pp[wid * 3 + 1] = accV;
        s_pp[wid * 3 + 2] = accR;
      }
      __syncthreads();
      if (tid < 4) {
        size_t o = lE + blk * 4 + tid;
        float K = s_pp[(2 * tid) * 3] + s_pp[(2 * tid + 1) * 3];
        float Vv = s_pp[(2 * tid) * 3 + 1] + s_pp[(2 * tid + 1) * 3 + 1];
        float R = s_pp[(2 * tid) * 3 + 2] + s_pp[(2 * tid + 1) * 3 + 2];
        float kx = expf(K), rx = expf(R) + 1.0f;
        float etf = expf(a.tf[o]), etd = expf(a.td[o]);
        float sb = a.stateb[o], sc = a.statec[o];
        float w_ = sb + etf * kx * Vv;
        float d_ = sc * rx + etf * kx * rx;
        cstoref(&ws_u[blk * 4 + tid], w_ / (d_ + 0.001f));
        out_bbb[o] = sb * etd + kx * Vv;
        out_ccc[o] = sc * etd + kx;
        out_aaa[o] = s_y[blk * 4 + tid];
      }
    }
    bar_arrive(a, ep, blk);
    {
      const float4 *orow = reinterpret_cast<const float4 *>(a.ovv + (lE + grow) * E);
      int b0 = h * 128 + lane;
      pw[0] = orow[b0]; pw[1] = orow[b0 + 64];
      asm volatile("" ::: "memory");
    }
    bar_wait(a, ep); ++ep;

    // ============ P2: sxx = x + ovv @ u ============
    {
      reinterpret_cast<float2 *>(s_a)[tid] =
          cload2(reinterpret_cast<const float2 *>(ws_u) + tid);
      __syncthreads();
      int b0 = h * 128 + lane;
      float acc = dot4(pw[0], s4a[b0]) + dot4(pw[1], s4a[b0 + 64]);
      acc = wred(acc);
      if (lane == 0) s_pp[wid] = acc;
      __syncthreads();
      if (tid < 4) {
        float sxx = s_x[blk * 4 + tid] + s_pp[2 * tid] + s_pp[2 * tid + 1];
        cstoref(&ws_sxx[blk * 4 + tid], sxx);
      }
    }
    bar_arrive(a, ep, blk);
    {
      const float *kfb = a.kf + (size_t)l * H * E;
      const float4 *k0 = reinterpret_cast<const float4 *>(kfb + (size_t)(blk * 16 + wid) * E);
      const float4 *k1 = reinterpret_cast<const float4 *>(kfb + (size_t)(blk * 16 + 8 + wid) * E);
      pw[0] = k0[lane];       pw[1] = k0[lane + 64];
      pw[2] = k0[lane + 128]; pw[3] = k0[lane + 192];
      pw[4] = k1[lane];       pw[5] = k1[lane + 64];
      pw[6] = k1[lane + 128]; pw[7] = k1[lane + 192];
      const float4 *rrow = reinterpret_cast<const float4 *>(a.rf + (lE + grow) * E);
      int b0 = h * 128 + lane;
      pw[8] = rrow[b0]; pw[9] = rrow[b0 + 64];
      asm volatile("" ::: "memory");
    }
    bar_wait(a, ep); ++ep;

    // ============ P3: LN2 + key_ffn (2 rows/wave) + receptance_ffn ============
    {
      float2 v = cload2(reinterpret_cast<const float2 *>(ws_sxx) + tid);
      float2 st = block_stats_v(v, s_x, s_red, tid, lane, wid);
#pragma unroll
      for (int j = 0; j < 2; ++j) {
        int e = tid + 512 * j;
        float xx = (s_x[e] - st.x) * st.y * a.ln2w[lE + e] + a.ln2b[lE + e];
        s_y[e] = xx;
        float sd = a.stated[lE + e];
        s_a[e] = xx + a.tmk[lE + e] * sd;
        s_a[1024 + e] = xx + a.tmr[lE + e] * sd;
      }
      __syncthreads();
      float k0 = dot4(pw[0], s4a[lane]) + dot4(pw[1], s4a[lane + 64]) +
                 dot4(pw[2], s4a[lane + 128]) + dot4(pw[3], s4a[lane + 192]);
      float k1 = dot4(pw[4], s4a[lane]) + dot4(pw[5], s4a[lane + 64]) +
                 dot4(pw[6], s4a[lane + 128]) + dot4(pw[7], s4a[lane + 192]);
      int b0 = h * 128 + lane;
      float ar_ = dot4(pw[8], s4a[256 + b0]) + dot4(pw[9], s4a[256 + b0 + 64]);
      k0 = wred(k0); k1 = wred(k1); ar_ = wred(ar_);
      if (lane == 0) {
        float t0 = fmaxf(k0, 0.f), t1 = fmaxf(k1, 0.f);
        cstoref(&ws_km[blk * 16 + wid], t0 * t0);
        cstoref(&ws_km[blk * 16 + 8 + wid], t1 * t1);
        s_pp[wid] = ar_;
      }
      __syncthreads();
      if (tid < 4) {
        s_rt[tid] = expf(s_pp[2 * tid] + s_pp[2 * tid + 1]) + 1.0f;
        out_ddd[lE + blk * 4 + tid] = s_y[blk * 4 + tid];
      }
    }
    bar_arrive(a, ep, blk);
    {
      const float4 *vrow = reinterpret_cast<const float4 *>(a.vf + (lE + grow) * H);
      int b0 = h * 512 + lane;
      pw[0] = vrow[b0];       pw[1] = vrow[b0 + 64];
      pw[2] = vrow[b0 + 128]; pw[3] = vrow[b0 + 192];
      pw[4] = vrow[b0 + 256]; pw[5] = vrow[b0 + 320];
      pw[6] = vrow[b0 + 384]; pw[7] = vrow[b0 + 448];
      asm volatile("" ::: "memory");
    }
    bar_wait(a, ep); ++ep;

    // ============ P4: x_next = sxx + (vf @ km) / rt ============
    {
      float4 km0, km1;
      cload4x2(km0, km1,
               reinterpret_cast<const float4 *>(ws_km) + tid,
               reinterpret_cast<const float4 *>(ws_km) + tid + 512);
      reinterpret_cast<float4 *>(s_a)[tid] = km0;
      reinterpret_cast<float4 *>(s_a)[tid + 512] = km1;
      __syncthreads();
      int b0 = h * 512 + lane;
      float acc = dot4(pw[0], s4a[b0]) + dot4(pw[1], s4a[b0 + 64]) +
                  dot4(pw[2], s4a[b0 + 128]) + dot4(pw[3], s4a[b0 + 192]) +
                  dot4(pw[4], s4a[b0 + 256]) + dot4(pw[5], s4a[b0 + 320]) +
                  dot4(pw[6], s4a[b0 + 384]) + dot4(pw[7], s4a[b0 + 448]);
      acc = wred(acc);
      if (lane == 0) s_pp[wid] = acc;
      __syncthreads();
      if (tid < 4) {
        float xn = s_x[blk * 4 + tid] + (s_pp[2 * tid] + s_pp[2 * tid + 1]) / s_rt[tid];
        cstoref(&ws_x[blk * 4 + tid], xn);
      }
    }
    bar_arrive(a, ep, blk);
    if (l < L - 1) {
      const size_t lE2 = (size_t)(l + 1) * E;
      const float4 *kr = reinterpret_cast<const float4 *>(a.ak + (lE2 + grow) * E);
      const float4 *vr = reinterpret_cast<const float4 *>(a.av + (lE2 + grow) * E);
      const float4 *rr = reinterpret_cast<const float4 *>(a.ar + (lE2 + grow) * E);
      int b0 = h * 128 + lane;
      pw[0] = kr[b0]; pw[1] = kr[b0 + 64];
      pw[2] = vr[b0]; pw[3] = vr[b0 + 64];
      pw[4] = rr[b0]; pw[5] = rr[b0 + 64];
      asm volatile("" ::: "memory");
    }
    bar_wait(a, ep); ++ep;
  }

  // ============ Final: LN + logits = post2 @ xfin (double-buffered) ============
  {
    float2 v = cload2(reinterpret_cast<const float2 *>(ws_x) + tid);
    float2 st = block_stats_v(v, s_x, s_red, tid, lane, wid);
#pragma unroll
    for (int j = 0; j < 2; ++j) {
      int e = tid + 512 * j;
      s_a[e] = (s_x[e] - st.x) * st.y * a.post0[e] + a.post1[e];
    }
    __syncthreads();

    const float4 *P2 = reinterpret_cast<const float4 *>(a.post2);
    const int gw = blk * 8 + wid;  // 0..2047
    int r0 = gw, r1 = gw + 2048;
    float4 A0[4], A1[4];
    loadrow(A0, P2, r0, lane);
    loadrow(A1, P2, r1 < V ? r1 : r0, lane);
    while (true) {
      int n0 = r0 + 4096, n1 = n0 + 2048;
      bool more = n0 < V;
      float4 B0[4], B1[4];
      if (more) {
        loadrow(B0, P2, n0, lane);
        loadrow(B1, P2, n1 < V ? n1 : n0, lane);
      }
      float a0 = dot4(A0[0], s4a[lane]) + dot4(A0[1], s4a[lane + 64]) +
                 dot4(A0[2], s4a[lane + 128]) + dot4(A0[3], s4a[lane + 192]);
      float a1 = dot4(A1[0], s4a[lane]) + dot4(A1[1], s4a[lane + 64]) +
                 dot4(A1[2], s4a[lane + 128]) + dot4(A1[3], s4a[lane + 192]);
      a0 = wred(a0); a1 = wred(a1);
      if (lane == 0) {
        out_logits[r0] = a0;
        if (r1 < V) out_logits[r1] = a1;
      }
      if (!more) break;
#pragma unroll
      for (int q = 0; q < 4; ++q) { A0[q] = B0[q]; A1[q] = B1[q]; }
      r0 = n0; r1 = n1;
    }
  }
}

extern "C" void kernel_launch(void *const *d_in, const int *in_sizes, int n_in,
                              void *d_out, int out_size, void *d_ws, size_t ws_size,
                              hipStream_t stream) {
  (void)in_sizes; (void)n_in; (void)out_size; (void)ws_size;
  Args a;
  a.statea = (const float *)d_in[0];
  a.stateb = (const float *)d_in[1];
  a.statec = (const float *)d_in[2];
  a.stated = (const float *)d_in[3];
  a.pre    = (const float *)d_in[4];
  a.ln1w   = (const float *)d_in[5];
  a.ln1b   = (const float *)d_in[6];
  a.ln2w   = (const float *)d_in[7];
  a.ln2b   = (const float *)d_in[8];
  a.ak     = (const float *)d_in[9];
  a.ar     = (const float *)d_in[10];
  a.av     = (const float *)d_in[11];
  a.kk     = (const float *)d_in[12];
  a.vv     = (const float *)d_in[13];
  a.rr     = (const float *)d_in[14];
  a.tf     = (const float *)d_in[15];
  a.td     = (const float *)d_in[16];
  a.ovv    = (const float *)d_in[17];
  a.tmk    = (const float *)d_in[18];
  a.tmr    = (const float *)d_in[19];
  a.kf     = (const float *)d_in[20];
  a.rf     = (const float *)d_in[21];
  a.vf     = (const float *)d_in[22];
  a.post0  = (const float *)d_in[23];
  a.post1  = (const float *)d_in[24];
  a.post2  = (const float *)d_in[25];
  a.token  = (const int *)d_in[26];
  a.out    = (float *)d_out;

  a.flags  = (unsigned *)d_ws;                 // 256 flags, 128 B stride = 32 KB
  a.ws     = (float *)((char *)d_ws + 32768);  // coherent data vectors

  hipMemsetAsync(d_ws, 0, 32768, stream);
  rwkv_fused<<<NBLK, NTHR, 0, stream>>>(a);
}